// Round 1
// baseline (1419.654 us; speedup 1.0000x reference)
//
#include <hip/hip_runtime.h>
#include <cstdint>
#include <cstddef>

#define BB 256
#define TT 128
#define AA 4
#define II 128
#define HH 256
#define K3 768  // 3*H

typedef __attribute__((ext_vector_type(8))) short short8;
typedef __attribute__((ext_vector_type(4))) float f32x4;

static __device__ __forceinline__ unsigned short f2bf(float f) {
  unsigned int b = __float_as_uint(f);
  return (unsigned short)((b + 0x7FFFu + ((b >> 16) & 1u)) >> 16);  // RNE
}

// fp32 -> bf16 weight conversion into workspace (W_ih then W_hh, row-major kept)
__global__ void wconv_kernel(const float* __restrict__ wih,
                             const float* __restrict__ whh,
                             unsigned short* __restrict__ o) {
  int i = blockIdx.x * 512 + threadIdx.x;
  float v = (i < K3 * II) ? wih[i] : whh[i - K3 * II];
  o[i] = f2bf(v);
}

// One block per batch element b; block owns agents a=0..3 across all T.
// 8 waves; wave w owns gate rows [96w, 96w+96) (6 MFMA 16-row tiles).
// MFMA 16x16x32 bf16: A = weight rows (lane&15 = row, k=(lane>>4)*8+e),
// B = h/x fragment   (lane&15 = col(agent), k=(lane>>4)*8+e),
// D: col = lane&15, row = (lane>>4)*4 + reg   [verified layout, m89].
template <int WSW>
__global__ __launch_bounds__(512, 2) void gru_kernel(
    const float* __restrict__ x,
    const void* __restrict__ init_raw,
    const float* __restrict__ wih_f,
    const float* __restrict__ whh_f,
    const float* __restrict__ bih_g,
    const float* __restrict__ bhh_g,
    const unsigned short* __restrict__ wb,
    float* __restrict__ out) {
  __shared__ alignas(16) unsigned short xs[AA][II + 8];   // x_t as bf16
  __shared__ alignas(16) unsigned short hsb[AA][HH + 8];  // h as bf16 (MFMA operand)
  __shared__ float hs32[AA][HH];                          // h fp32 (z*h path)
  __shared__ float gi_s[K3][5];                           // stride-5: no bank conflict
  __shared__ float gh_s[K3][5];
  __shared__ float bihs[K3];
  __shared__ float bhhs[K3];
  __shared__ unsigned char msk[TT];
  __shared__ int detf[3];

  const int tid = threadIdx.x;
  const int b = blockIdx.x;

  if (tid < 3) detf[tid] = 0;
  for (int i = tid; i < K3; i += 512) { bihs[i] = bih_g[i]; bhhs[i] = bhh_g[i]; }
  for (int i = tid; i < AA * HH; i += 512) {
    hs32[i >> 8][i & 255] = 0.f;
    hsb[i >> 8][i & 255] = 0;
  }
  __syncthreads();

  // ---- is_init layout probe: uint8 / int32|fp32 / int64. Reads 8192 words,
  // in-bounds under every candidate layout (byte buffer = exactly 32 KiB).
  {
    const unsigned int* wq = (const unsigned int*)init_raw;
    int notf = 0, gt1 = 0, oddnz = 0;
    for (int i = tid; i < (BB * TT / 4); i += 512) {
      unsigned int v = wq[i];
      notf |= (v != 0u && v != 0x3F800000u);
      gt1 |= (v > 1u);
      if (i & 1) oddnz |= (v != 0u);
    }
    if (notf) atomicOr(&detf[0], 1);
    if (gt1) atomicOr(&detf[1], 1);
    if (oddnz) atomicOr(&detf[2], 1);
  }
  __syncthreads();
  if (tid < TT) {
    // all words in {0,1.0f} -> fp32 (word-indexed, nonzero test == int32 path)
    // else any word>1 -> packed bytes; else odd words nonzero -> int32; else int64
    int layout = (!detf[0]) ? 1 : (detf[1] ? 0 : (detf[2] ? 1 : 2));
    int e = b * TT + tid;
    unsigned int v;
    if (layout == 0)      v = ((const unsigned char*)init_raw)[e];
    else if (layout == 1) v = ((const unsigned int*)init_raw)[e];
    else                  v = ((const unsigned int*)init_raw)[2 * e];
    msk[tid] = v ? 1 : 0;
  }
  __syncthreads();

  const int l = tid & 63;
  const int w = tid >> 6;
  const int c = l & 15;
  const int g = l >> 4;
  const bool act = (c < AA);
  const int xa = tid >> 7, xi = tid & 127;
  const float* xrow = x + (size_t)b * TT * AA * II;
  const unsigned short* wihb = wb;
  const unsigned short* whhb = wb + K3 * II;

  for (int t = 0; t < TT; ++t) {
    // phase 1: stage x_t (coalesced 2KB) as bf16; reset h where is_init
    xs[xa][xi] = f2bf(xrow[(size_t)t * (AA * II) + tid]);
    if (msk[t]) {
      for (int i = tid; i < AA * HH; i += 512) {
        hs32[i >> 8][i & 255] = 0.f;
        hsb[i >> 8][i & 255] = 0;
      }
    }
    __syncthreads();

    // phase 2: MFMA. B-fragments from LDS (agent col = c, zeros for c>=4)
    short8 bx[4], bh[8];
    if (act) {
#pragma unroll
      for (int kk = 0; kk < 4; ++kk) bx[kk] = *(const short8*)&xs[c][kk * 32 + g * 8];
#pragma unroll
      for (int kk = 0; kk < 8; ++kk) bh[kk] = *(const short8*)&hsb[c][kk * 32 + g * 8];
    } else {
#pragma unroll
      for (int kk = 0; kk < 4; ++kk) bx[kk] = (short8)0;
#pragma unroll
      for (int kk = 0; kk < 8; ++kk) bh[kk] = (short8)0;
    }

#pragma unroll
    for (int kt = 0; kt < 6; ++kt) {  // gi: K=128 -> 4 k-steps
      const int ar = w * 96 + kt * 16 + c;
      f32x4 acc = {0.f, 0.f, 0.f, 0.f};
#pragma unroll
      for (int kk = 0; kk < 4; ++kk) {
        short8 aw;
        if (WSW) {
          aw = *(const short8*)&wihb[(size_t)ar * II + kk * 32 + g * 8];
        } else {
          const float* p = &wih_f[(size_t)ar * II + kk * 32 + g * 8];
#pragma unroll
          for (int e = 0; e < 8; ++e) aw[e] = (short)f2bf(p[e]);
        }
        acc = __builtin_amdgcn_mfma_f32_16x16x32_bf16(aw, bx[kk], acc, 0, 0, 0);
      }
      if (act) {
        const int dr = w * 96 + kt * 16 + g * 4;
#pragma unroll
        for (int r = 0; r < 4; ++r) gi_s[dr + r][c] = acc[r];
      }
    }

#pragma unroll
    for (int kt = 0; kt < 6; ++kt) {  // gh: K=256 -> 8 k-steps
      const int ar = w * 96 + kt * 16 + c;
      f32x4 acc = {0.f, 0.f, 0.f, 0.f};
#pragma unroll
      for (int kk = 0; kk < 8; ++kk) {
        short8 aw;
        if (WSW) {
          aw = *(const short8*)&whhb[(size_t)ar * HH + kk * 32 + g * 8];
        } else {
          const float* p = &whh_f[(size_t)ar * HH + kk * 32 + g * 8];
#pragma unroll
          for (int e = 0; e < 8; ++e) aw[e] = (short)f2bf(p[e]);
        }
        acc = __builtin_amdgcn_mfma_f32_16x16x32_bf16(aw, bh[kk], acc, 0, 0, 0);
      }
      if (act) {
        const int dr = w * 96 + kt * 16 + g * 4;
#pragma unroll
        for (int r = 0; r < 4; ++r) gh_s[dr + r][c] = acc[r];
      }
    }
    __syncthreads();

    // phase 3: gates + pointwise (fp32), 1024 (a,j) pairs over 512 threads
#pragma unroll
    for (int it = 0; it < 2; ++it) {
      const int idx = it * 512 + tid;
      const int a = idx >> 8, j = idx & 255;
      const float ir = gi_s[j][a] + bihs[j];
      const float iz = gi_s[HH + j][a] + bihs[HH + j];
      const float inn = gi_s[2 * HH + j][a] + bihs[2 * HH + j];
      const float hr = gh_s[j][a] + bhhs[j];
      const float hz = gh_s[HH + j][a] + bhhs[HH + j];
      const float hn = gh_s[2 * HH + j][a] + bhhs[2 * HH + j];
      const float r = 1.f / (1.f + __expf(-(ir + hr)));
      const float z = 1.f / (1.f + __expf(-(iz + hz)));
      const float pre = inn + r * hn;
      const float ea = __expf(-2.f * fabsf(pre));
      float n = (1.f - ea) / (1.f + ea);
      n = (pre < 0.f) ? -n : n;
      const float hold = hs32[a][j];
      const float hnew = (1.f - z) * n + z * hold;
      hs32[a][j] = hnew;
      hsb[a][j] = f2bf(hnew);
      out[(((size_t)b * TT + t) * AA + a) * HH + j] = hnew;
      if (t == TT - 1)
        out[(size_t)BB * TT * AA * HH + ((size_t)b * AA + a) * HH + j] = hnew;
    }
    __syncthreads();
  }
}

extern "C" void kernel_launch(void* const* d_in, const int* in_sizes, int n_in,
                              void* d_out, int out_size, void* d_ws, size_t ws_size,
                              hipStream_t stream) {
  (void)in_sizes; (void)n_in; (void)out_size;
  const float* x = (const float*)d_in[0];
  const void* is_init = d_in[1];
  const float* wih = (const float*)d_in[2];
  const float* whh = (const float*)d_in[3];
  const float* bih = (const float*)d_in[4];
  const float* bhh = (const float*)d_in[5];
  float* out = (float*)d_out;

  const size_t wneed = (size_t)(K3 * II + K3 * HH) * sizeof(unsigned short);  // 589,824 B
  if (ws_size >= wneed) {
    unsigned short* wb = (unsigned short*)d_ws;
    wconv_kernel<<<(K3 * II + K3 * HH) / 512, 512, 0, stream>>>(wih, whh, wb);
    gru_kernel<1><<<BB, 512, 0, stream>>>(x, is_init, wih, whh, bih, bhh, wb, out);
  } else {
    gru_kernel<0><<<BB, 512, 0, stream>>>(x, is_init, wih, whh, bih, bhh, nullptr, out);
  }
}

// Round 2
// 562.301 us; speedup vs baseline: 2.5247x; 2.5247x over previous
//
#include <hip/hip_runtime.h>
#include <cstdint>
#include <cstddef>

#define BB 256
#define TT 128
#define AA 4
#define II 128
#define HH 256
#define K3 768  // 3*H

typedef __attribute__((ext_vector_type(8))) short short8;
typedef __attribute__((ext_vector_type(4))) float f32x4;
typedef __attribute__((ext_vector_type(4))) unsigned short ushort4_t;

static __device__ __forceinline__ unsigned short f2bf(float f) {
  unsigned int b = __float_as_uint(f);
  return (unsigned short)((b + 0x7FFFu + ((b >> 16) & 1u)) >> 16);  // RNE
}
static __device__ __forceinline__ float bf2f(unsigned short u) {
  return __uint_as_float(((unsigned int)u) << 16);
}

// fp32 -> bf16 weight conversion into workspace (W_ih then W_hh, row-major kept)
__global__ void wconv_kernel(const float* __restrict__ wih,
                             const float* __restrict__ whh,
                             unsigned short* __restrict__ o) {
  int i = blockIdx.x * 512 + threadIdx.x;
  float v = (i < K3 * II) ? wih[i] : whh[i - K3 * II];
  o[i] = f2bf(v);
}

// ---------------- Phase A: gi = x * W_ih^T + b_ih, stored bf16 ----------------
// grid 2048, 512 thr. Block handles 64 (b,t,a) rows; 4 chunks of 16 cols.
__global__ __launch_bounds__(512, 2) void gi_kernel(
    const float* __restrict__ x,
    const float* __restrict__ bih_g,
    const unsigned short* __restrict__ wb,   // W_ih bf16 at ws[0]
    unsigned short* __restrict__ gi) {
  __shared__ alignas(16) unsigned short xs[64][144];
  __shared__ alignas(16) unsigned short gst[16][792];
  __shared__ float bihs[K3];

  const int tid = threadIdx.x;
  const int l = tid & 63, w = tid >> 6;
  const int c = l & 15, g = l >> 4;
  const size_t m0 = (size_t)blockIdx.x * 64;

  for (int i = tid; i < K3; i += 512) bihs[i] = bih_g[i];
  for (int i = tid; i < 64 * 128; i += 512) {
    int row = i >> 7, col = i & 127;
    xs[row][col] = f2bf(x[m0 * 128 + i]);
  }
  // W_ih fragments: wave w owns gate rows [96w, 96w+96) = 6 tiles
  short8 wf[6][4];
#pragma unroll
  for (int kt = 0; kt < 6; ++kt) {
    int row = 96 * w + kt * 16 + c;
#pragma unroll
    for (int kk = 0; kk < 4; ++kk)
      wf[kt][kk] = *(const short8*)&wb[(size_t)row * II + kk * 32 + g * 8];
  }
  __syncthreads();

  for (int chunk = 0; chunk < 4; ++chunk) {
    short8 bx[4];
#pragma unroll
    for (int kk = 0; kk < 4; ++kk)
      bx[kk] = *(const short8*)&xs[chunk * 16 + c][kk * 32 + g * 8];
    f32x4 acc[6];
#pragma unroll
    for (int kt = 0; kt < 6; ++kt) acc[kt] = (f32x4){0.f, 0.f, 0.f, 0.f};
#pragma unroll
    for (int kt = 0; kt < 6; ++kt)
#pragma unroll
      for (int kk = 0; kk < 4; ++kk)
        acc[kt] = __builtin_amdgcn_mfma_f32_16x16x32_bf16(wf[kt][kk], bx[kk], acc[kt], 0, 0, 0);
    // stage D tiles (col=c, row=g*4+r) into gst with b_ih folded
#pragma unroll
    for (int kt = 0; kt < 6; ++kt) {
      int gate0 = 96 * w + kt * 16 + g * 4;
      ushort4_t p;
#pragma unroll
      for (int r = 0; r < 4; ++r) p[r] = f2bf(acc[kt][r] + bihs[gate0 + r]);
      *(ushort4_t*)&gst[c][gate0] = p;
    }
    __syncthreads();
    // coalesced global write: 16 rows x 768 bf16
    for (int i = tid; i < 16 * 96; i += 512) {
      int row = i / 96, seg = i - row * 96;
      *(short8*)(gi + (m0 + chunk * 16 + row) * K3 + seg * 8) =
          *(const short8*)&gst[row][seg * 8];
    }
    __syncthreads();
  }
}

// ---------------- Phase B: recurrence, weights resident ----------------
// grid 256 (block = batch b, 4 agent seqs), 512 thr (8 waves).
// Wave w owns units j in [32w, 32w+32): r/z tiles in regs, n tiles in LDS
// (fragment-order, conflict-free). Pointwise fully in-register per lane.
__global__ __launch_bounds__(512, 2) void rnn_kernel(
    const void* __restrict__ init_raw,
    const float* __restrict__ bhh_g,
    const unsigned short* __restrict__ wsb,  // ws bf16 base: [W_ih | W_hh]
    const unsigned short* __restrict__ gi,
    float* __restrict__ out) {
  extern __shared__ char smem[];
  unsigned short* wlds = (unsigned short*)smem;                 // 131072 B
  float* hs32 = (float*)(smem + 131072);                        // 4096 B
  float* bhhs = (float*)(smem + 135168);                        // 3072 B
  unsigned short* hsb = (unsigned short*)(smem + 138240);       // [4][264] 2112 B
  unsigned char* msk = (unsigned char*)(smem + 140352);         // 128 B
  int* detf = (int*)(smem + 140480);                            // 12 B

  const int tid = threadIdx.x;
  const int b = blockIdx.x;
  const unsigned short* whh_b = wsb + K3 * II;

  if (tid < 3) detf[tid] = 0;
  for (int i = tid; i < K3; i += 512) bhhs[i] = bhh_g[i];
  for (int i = tid; i < AA * HH; i += 512) hs32[i] = 0.f;
  for (int i = tid; i < AA * 264; i += 512) hsb[i] = 0;
  // stage n-gate rows [512,768) into LDS in fragment order: idx f ->
  // (w2, kt, kk, lane); addr = f*16 bytes (lane-contiguous => conflict-free)
  for (int f = tid; f < 8192; f += 512) {
    int lane = f & 63, kk = (f >> 6) & 7, kt = (f >> 9) & 1, w2 = f >> 10;
    int row = 512 + w2 * 32 + kt * 16 + (lane & 15);
    int col = kk * 32 + (lane >> 4) * 8;
    *(short8*)(wlds + (size_t)f * 8) = *(const short8*)&whh_b[(size_t)row * HH + col];
  }

  // ---- is_init layout probe (identical to verified round-1 logic) ----
  {
    const unsigned int* wq = (const unsigned int*)init_raw;
    int notf = 0, gt1 = 0, oddnz = 0;
    for (int i = tid; i < (BB * TT / 4); i += 512) {
      unsigned int v = wq[i];
      notf |= (v != 0u && v != 0x3F800000u);
      gt1 |= (v > 1u);
      if (i & 1) oddnz |= (v != 0u);
    }
    if (notf) atomicOr(&detf[0], 1);
    if (gt1) atomicOr(&detf[1], 1);
    if (oddnz) atomicOr(&detf[2], 1);
  }
  __syncthreads();
  if (tid < TT) {
    int layout = (!detf[0]) ? 1 : (detf[1] ? 0 : (detf[2] ? 1 : 2));
    int e = b * TT + tid;
    unsigned int v;
    if (layout == 0)      v = ((const unsigned char*)init_raw)[e];
    else if (layout == 1) v = ((const unsigned int*)init_raw)[e];
    else                  v = ((const unsigned int*)init_raw)[2 * e];
    msk[tid] = v ? 1 : 0;
  }

  const int l = tid & 63, w = tid >> 6;
  const int c = l & 15, g = l >> 4;
  const bool act = (c < AA);

  // resident W_hh register tiles: r-gate rows {32w, 32w+16}, z-gate {256+32w, 256+32w+16}
  short8 wreg[4][8];
#pragma unroll
  for (int tile = 0; tile < 4; ++tile) {
    int row = (tile >> 1) * 256 + 32 * w + (tile & 1) * 16 + c;
#pragma unroll
    for (int kk = 0; kk < 8; ++kk)
      wreg[tile][kk] = *(const short8*)&whh_b[(size_t)row * HH + kk * 32 + g * 8];
  }
  const unsigned short* wl = wlds + w * 8192 + l * 8;  // my n-gate frags
  __syncthreads();

  for (int t = 0; t < TT; ++t) {
    if (msk[t]) {
      for (int i = tid; i < AA * HH; i += 512) hs32[i] = 0.f;
      for (int i = tid; i < AA * 264; i += 512) hsb[i] = 0;
      __syncthreads();
    }
    // read h fragments (all waves) BEFORE the barrier that allows h writes
    short8 bh[8];
    const unsigned short* hrow = hsb + (c & 3) * 264;
#pragma unroll
    for (int kk = 0; kk < 8; ++kk) bh[kk] = *(const short8*)(hrow + kk * 32 + g * 8);
    __syncthreads();

    // gi prefetch (global, hidden under MFMAs)
    ushort4_t gr_[2], gz_[2], gn_[2];
    if (act) {
      const unsigned short* gp = gi + ((size_t)(b * TT + t) * AA + c) * K3;
      int j0w = 32 * w + g * 4;
      gr_[0] = *(const ushort4_t*)(gp + j0w);
      gr_[1] = *(const ushort4_t*)(gp + j0w + 16);
      gz_[0] = *(const ushort4_t*)(gp + HH + j0w);
      gz_[1] = *(const ushort4_t*)(gp + HH + j0w + 16);
      gn_[0] = *(const ushort4_t*)(gp + 2 * HH + j0w);
      gn_[1] = *(const ushort4_t*)(gp + 2 * HH + j0w + 16);
    }

    f32x4 aR[2], aZ[2], aN[2];
#pragma unroll
    for (int k2 = 0; k2 < 2; ++k2) {
      aR[k2] = (f32x4){0.f, 0.f, 0.f, 0.f};
      aZ[k2] = (f32x4){0.f, 0.f, 0.f, 0.f};
      aN[k2] = (f32x4){0.f, 0.f, 0.f, 0.f};
    }
#pragma unroll
    for (int kk = 0; kk < 8; ++kk) {
      aR[0] = __builtin_amdgcn_mfma_f32_16x16x32_bf16(wreg[0][kk], bh[kk], aR[0], 0, 0, 0);
      aR[1] = __builtin_amdgcn_mfma_f32_16x16x32_bf16(wreg[1][kk], bh[kk], aR[1], 0, 0, 0);
      aZ[0] = __builtin_amdgcn_mfma_f32_16x16x32_bf16(wreg[2][kk], bh[kk], aZ[0], 0, 0, 0);
      aZ[1] = __builtin_amdgcn_mfma_f32_16x16x32_bf16(wreg[3][kk], bh[kk], aZ[1], 0, 0, 0);
      short8 an0 = *(const short8*)(wl + kk * 512);
      short8 an1 = *(const short8*)(wl + 4096 + kk * 512);
      aN[0] = __builtin_amdgcn_mfma_f32_16x16x32_bf16(an0, bh[kk], aN[0], 0, 0, 0);
      aN[1] = __builtin_amdgcn_mfma_f32_16x16x32_bf16(an1, bh[kk], aN[1], 0, 0, 0);
    }

    if (act) {
#pragma unroll
      for (int k2 = 0; k2 < 2; ++k2) {
        const int j0 = 32 * w + k2 * 16 + g * 4;
        f32x4 hold = *(const f32x4*)&hs32[c * HH + j0];
        f32x4 hnv;
        ushort4_t hb;
#pragma unroll
        for (int r = 0; r < 4; ++r) {
          const int j = j0 + r;
          const float pr = bf2f(gr_[k2][r]) + aR[k2][r] + bhhs[j];
          const float pz = bf2f(gz_[k2][r]) + aZ[k2][r] + bhhs[HH + j];
          const float rs = 1.f / (1.f + __expf(-pr));
          const float zs = 1.f / (1.f + __expf(-pz));
          const float hn = aN[k2][r] + bhhs[2 * HH + j];
          const float pre = bf2f(gn_[k2][r]) + rs * hn;
          const float ea = __expf(-2.f * fabsf(pre));
          float nn = (1.f - ea) / (1.f + ea);
          nn = (pre < 0.f) ? -nn : nn;
          const float hnew = (1.f - zs) * nn + zs * hold[r];
          hnv[r] = hnew;
          hb[r] = f2bf(hnew);
        }
        *(f32x4*)&hs32[c * HH + j0] = hnv;
        *(ushort4_t*)&hsb[c * 264 + j0] = hb;
        *(f32x4*)&out[(((size_t)b * TT + t) * AA + c) * HH + j0] = hnv;
        if (t == TT - 1)
          *(f32x4*)&out[(size_t)BB * TT * AA * HH + ((size_t)b * AA + c) * HH + j0] = hnv;
      }
    }
    __syncthreads();
  }
}

// ---------------- Fallback: round-1 kernel (known-pass) ----------------
template <int WSW>
__global__ __launch_bounds__(512, 2) void gru_kernel(
    const float* __restrict__ x,
    const void* __restrict__ init_raw,
    const float* __restrict__ wih_f,
    const float* __restrict__ whh_f,
    const float* __restrict__ bih_g,
    const float* __restrict__ bhh_g,
    const unsigned short* __restrict__ wb,
    float* __restrict__ out) {
  __shared__ alignas(16) unsigned short xs[AA][II + 8];
  __shared__ alignas(16) unsigned short hsb[AA][HH + 8];
  __shared__ float hs32[AA][HH];
  __shared__ float gi_s[K3][5];
  __shared__ float gh_s[K3][5];
  __shared__ float bihs[K3];
  __shared__ float bhhs[K3];
  __shared__ unsigned char msk[TT];
  __shared__ int detf[3];

  const int tid = threadIdx.x;
  const int b = blockIdx.x;

  if (tid < 3) detf[tid] = 0;
  for (int i = tid; i < K3; i += 512) { bihs[i] = bih_g[i]; bhhs[i] = bhh_g[i]; }
  for (int i = tid; i < AA * HH; i += 512) {
    hs32[i >> 8][i & 255] = 0.f;
    hsb[i >> 8][i & 255] = 0;
  }
  __syncthreads();
  {
    const unsigned int* wq = (const unsigned int*)init_raw;
    int notf = 0, gt1 = 0, oddnz = 0;
    for (int i = tid; i < (BB * TT / 4); i += 512) {
      unsigned int v = wq[i];
      notf |= (v != 0u && v != 0x3F800000u);
      gt1 |= (v > 1u);
      if (i & 1) oddnz |= (v != 0u);
    }
    if (notf) atomicOr(&detf[0], 1);
    if (gt1) atomicOr(&detf[1], 1);
    if (oddnz) atomicOr(&detf[2], 1);
  }
  __syncthreads();
  if (tid < TT) {
    int layout = (!detf[0]) ? 1 : (detf[1] ? 0 : (detf[2] ? 1 : 2));
    int e = b * TT + tid;
    unsigned int v;
    if (layout == 0)      v = ((const unsigned char*)init_raw)[e];
    else if (layout == 1) v = ((const unsigned int*)init_raw)[e];
    else                  v = ((const unsigned int*)init_raw)[2 * e];
    msk[tid] = v ? 1 : 0;
  }
  __syncthreads();

  const int l = tid & 63;
  const int w = tid >> 6;
  const int c = l & 15;
  const int g = l >> 4;
  const bool act = (c < AA);
  const int xa = tid >> 7, xi = tid & 127;
  const float* xrow = x + (size_t)b * TT * AA * II;
  const unsigned short* wihb = wb;
  const unsigned short* whhb = wb + K3 * II;

  for (int t = 0; t < TT; ++t) {
    xs[xa][xi] = f2bf(xrow[(size_t)t * (AA * II) + tid]);
    if (msk[t]) {
      for (int i = tid; i < AA * HH; i += 512) {
        hs32[i >> 8][i & 255] = 0.f;
        hsb[i >> 8][i & 255] = 0;
      }
    }
    __syncthreads();

    short8 bx[4], bh[8];
    if (act) {
#pragma unroll
      for (int kk = 0; kk < 4; ++kk) bx[kk] = *(const short8*)&xs[c][kk * 32 + g * 8];
#pragma unroll
      for (int kk = 0; kk < 8; ++kk) bh[kk] = *(const short8*)&hsb[c][kk * 32 + g * 8];
    } else {
#pragma unroll
      for (int kk = 0; kk < 4; ++kk) bx[kk] = (short8)0;
#pragma unroll
      for (int kk = 0; kk < 8; ++kk) bh[kk] = (short8)0;
    }

#pragma unroll
    for (int kt = 0; kt < 6; ++kt) {
      const int ar = w * 96 + kt * 16 + c;
      f32x4 acc = {0.f, 0.f, 0.f, 0.f};
#pragma unroll
      for (int kk = 0; kk < 4; ++kk) {
        short8 aw;
        if (WSW) {
          aw = *(const short8*)&wihb[(size_t)ar * II + kk * 32 + g * 8];
        } else {
          const float* p = &wih_f[(size_t)ar * II + kk * 32 + g * 8];
#pragma unroll
          for (int e = 0; e < 8; ++e) aw[e] = (short)f2bf(p[e]);
        }
        acc = __builtin_amdgcn_mfma_f32_16x16x32_bf16(aw, bx[kk], acc, 0, 0, 0);
      }
      if (act) {
        const int dr = w * 96 + kt * 16 + g * 4;
#pragma unroll
        for (int r = 0; r < 4; ++r) gi_s[dr + r][c] = acc[r];
      }
    }

#pragma unroll
    for (int kt = 0; kt < 6; ++kt) {
      const int ar = w * 96 + kt * 16 + c;
      f32x4 acc = {0.f, 0.f, 0.f, 0.f};
#pragma unroll
      for (int kk = 0; kk < 8; ++kk) {
        short8 aw;
        if (WSW) {
          aw = *(const short8*)&whhb[(size_t)ar * HH + kk * 32 + g * 8];
        } else {
          const float* p = &whh_f[(size_t)ar * HH + kk * 32 + g * 8];
#pragma unroll
          for (int e = 0; e < 8; ++e) aw[e] = (short)f2bf(p[e]);
        }
        acc = __builtin_amdgcn_mfma_f32_16x16x32_bf16(aw, bh[kk], acc, 0, 0, 0);
      }
      if (act) {
        const int dr = w * 96 + kt * 16 + g * 4;
#pragma unroll
        for (int r = 0; r < 4; ++r) gh_s[dr + r][c] = acc[r];
      }
    }
    __syncthreads();

#pragma unroll
    for (int it = 0; it < 2; ++it) {
      const int idx = it * 512 + tid;
      const int a = idx >> 8, j = idx & 255;
      const float ir = gi_s[j][a] + bihs[j];
      const float iz = gi_s[HH + j][a] + bihs[HH + j];
      const float inn = gi_s[2 * HH + j][a] + bihs[2 * HH + j];
      const float hr = gh_s[j][a] + bhhs[j];
      const float hz = gh_s[HH + j][a] + bhhs[HH + j];
      const float hn = gh_s[2 * HH + j][a] + bhhs[2 * HH + j];
      const float r = 1.f / (1.f + __expf(-(ir + hr)));
      const float z = 1.f / (1.f + __expf(-(iz + hz)));
      const float pre = inn + r * hn;
      const float ea = __expf(-2.f * fabsf(pre));
      float n = (1.f - ea) / (1.f + ea);
      n = (pre < 0.f) ? -n : n;
      const float hold = hs32[a][j];
      const float hnew = (1.f - z) * n + z * hold;
      hs32[a][j] = hnew;
      hsb[a][j] = f2bf(hnew);
      out[(((size_t)b * TT + t) * AA + a) * HH + j] = hnew;
      if (t == TT - 1)
        out[(size_t)BB * TT * AA * HH + ((size_t)b * AA + a) * HH + j] = hnew;
    }
    __syncthreads();
  }
}

extern "C" void kernel_launch(void* const* d_in, const int* in_sizes, int n_in,
                              void* d_out, int out_size, void* d_ws, size_t ws_size,
                              hipStream_t stream) {
  (void)in_sizes; (void)n_in; (void)out_size;
  const float* x = (const float*)d_in[0];
  const void* is_init = d_in[1];
  const float* wih = (const float*)d_in[2];
  const float* whh = (const float*)d_in[3];
  const float* bih = (const float*)d_in[4];
  const float* bhh = (const float*)d_in[5];
  float* out = (float*)d_out;

  const size_t W_ELS = (size_t)(K3 * II + K3 * HH);        // 294,912
  const size_t W_BYTES = W_ELS * 2;                        // 589,824
  const size_t GI_BYTES = (size_t)BB * TT * AA * K3 * 2;   // 201,326,592
  const int SMEM = 140544;

  if (ws_size >= W_BYTES + GI_BYTES) {
    hipError_t e = hipFuncSetAttribute(
        (const void*)rnn_kernel, hipFuncAttributeMaxDynamicSharedMemorySize, SMEM);
    if (e == hipSuccess) {
      unsigned short* wb = (unsigned short*)d_ws;
      unsigned short* gi = wb + W_ELS;
      wconv_kernel<<<(int)(W_ELS / 512), 512, 0, stream>>>(wih, whh, wb);
      gi_kernel<<<2048, 512, 0, stream>>>(x, bih, wb, gi);
      rnn_kernel<<<BB, 512, SMEM, stream>>>(is_init, bhh, wb, gi, out);
      return;
    }
  }
  // fallback (round-1 verified path)
  if (ws_size >= W_BYTES) {
    unsigned short* wb = (unsigned short*)d_ws;
    wconv_kernel<<<(int)(W_ELS / 512), 512, 0, stream>>>(wih, whh, wb);
    gru_kernel<1><<<BB, 512, 0, stream>>>(x, is_init, wih, whh, bih, bhh, wb, out);
  } else {
    gru_kernel<0><<<BB, 512, 0, stream>>>(x, is_init, wih, whh, bih, bhh, nullptr, out);
  }
}

// Round 3
// 425.452 us; speedup vs baseline: 3.3368x; 1.3217x over previous
//
#include <hip/hip_runtime.h>
#include <cstdint>
#include <cstddef>

#define BB 256
#define TT 128
#define AA 4
#define II 128
#define HH 256
#define K3 768  // 3*H

typedef __attribute__((ext_vector_type(8))) short short8;
typedef __attribute__((ext_vector_type(4))) float f32x4;
typedef __attribute__((ext_vector_type(4))) unsigned short ushort4_t;

static __device__ __forceinline__ unsigned short f2bf(float f) {
  unsigned int b = __float_as_uint(f);
  return (unsigned short)((b + 0x7FFFu + ((b >> 16) & 1u)) >> 16);  // RNE
}
static __device__ __forceinline__ float bf2f(unsigned short u) {
  return __uint_as_float(((unsigned int)u) << 16);
}

// fp32 -> bf16 weight conversion into workspace (W_ih then W_hh, row-major kept)
__global__ void wconv_kernel(const float* __restrict__ wih,
                             const float* __restrict__ whh,
                             unsigned short* __restrict__ o) {
  int i = blockIdx.x * 512 + threadIdx.x;
  float v = (i < K3 * II) ? wih[i] : whh[i - K3 * II];
  o[i] = f2bf(v);
}

// ---------------- Phase A: gi = x * W_ih^T + b_ih (+ b_hh for r,z), bf16 ----
// grid 2048, 512 thr. Block handles 64 (b,t,a) rows; 4 chunks of 16 cols.
__global__ __launch_bounds__(512, 2) void gi_kernel(
    const float* __restrict__ x,
    const float* __restrict__ bih_g,
    const float* __restrict__ bhh_g,
    const unsigned short* __restrict__ wb,   // W_ih bf16 at ws[0]
    unsigned short* __restrict__ gi) {
  __shared__ alignas(16) unsigned short xs[64][144];
  __shared__ alignas(16) unsigned short gst[16][792];
  __shared__ float bihs[K3];

  const int tid = threadIdx.x;
  const int l = tid & 63, w = tid >> 6;
  const int c = l & 15, g = l >> 4;
  const size_t m0 = (size_t)blockIdx.x * 64;

  // fold b_ih always; fold b_hh for r,z gates (rows < 512). n-gate b_hh is
  // multiplied by r in the cell, so it cannot be folded here.
  for (int i = tid; i < K3; i += 512)
    bihs[i] = bih_g[i] + (i < 2 * HH ? bhh_g[i] : 0.f);
  for (int i = tid; i < 64 * 128; i += 512) {
    int row = i >> 7, col = i & 127;
    xs[row][col] = f2bf(x[m0 * 128 + i]);
  }
  short8 wf[6][4];
#pragma unroll
  for (int kt = 0; kt < 6; ++kt) {
    int row = 96 * w + kt * 16 + c;
#pragma unroll
    for (int kk = 0; kk < 4; ++kk)
      wf[kt][kk] = *(const short8*)&wb[(size_t)row * II + kk * 32 + g * 8];
  }
  __syncthreads();

  for (int chunk = 0; chunk < 4; ++chunk) {
    short8 bx[4];
#pragma unroll
    for (int kk = 0; kk < 4; ++kk)
      bx[kk] = *(const short8*)&xs[chunk * 16 + c][kk * 32 + g * 8];
    f32x4 acc[6];
#pragma unroll
    for (int kt = 0; kt < 6; ++kt) acc[kt] = (f32x4){0.f, 0.f, 0.f, 0.f};
#pragma unroll
    for (int kt = 0; kt < 6; ++kt)
#pragma unroll
      for (int kk = 0; kk < 4; ++kk)
        acc[kt] = __builtin_amdgcn_mfma_f32_16x16x32_bf16(wf[kt][kk], bx[kk], acc[kt], 0, 0, 0);
#pragma unroll
    for (int kt = 0; kt < 6; ++kt) {
      int gate0 = 96 * w + kt * 16 + g * 4;
      ushort4_t p;
#pragma unroll
      for (int r = 0; r < 4; ++r) p[r] = f2bf(acc[kt][r] + bihs[gate0 + r]);
      *(ushort4_t*)&gst[c][gate0] = p;
    }
    __syncthreads();
    for (int i = tid; i < 16 * 96; i += 512) {
      int row = i / 96, seg = i - row * 96;
      *(short8*)(gi + (m0 + chunk * 16 + row) * K3 + seg * 8) =
          *(const short8*)&gst[row][seg * 8];
    }
    __syncthreads();
  }
}

// ---------------- Phase B: recurrence ----------------
// grid 256 (block = batch b), 512 thr (8 waves). Wave w owns units
// j in [32w,32w+32): r/z W_hh tiles in regs(AGPRs), n tiles in LDS frag-order.
// h fp32 lives in owner-lane registers; h bf16 double-buffered in LDS
// fragment-order layout [buf][kk][a][g]*16B (conflict-free reads/writes).
// ONE barrier per timestep. is_init => skip the whole recurrent GEMM.
__global__ __launch_bounds__(512, 2) void rnn_kernel(
    const void* __restrict__ init_raw,
    const float* __restrict__ bhh_g,
    const unsigned short* __restrict__ wsb,  // ws bf16 base: [W_ih | W_hh]
    const unsigned short* __restrict__ gi,
    float* __restrict__ out) {
  extern __shared__ char smem[];
  unsigned short* wlds = (unsigned short*)smem;             // 131072 B (n-gate W)
  unsigned short* hsb = (unsigned short*)(smem + 131072);   // 2 bufs x 2048 B
  unsigned char* msk = (unsigned char*)(smem + 135168);     // 128 B
  int* detf = (int*)(smem + 135296);                        // 12 B

  const int tid = threadIdx.x;
  const int b = blockIdx.x;
  const unsigned short* whh_b = wsb + K3 * II;

  if (tid < 3) detf[tid] = 0;
  for (int i = tid; i < 2048; i += 512) *(unsigned short*)&hsb[i] = 0;
  // n-gate rows [512,768) staged in fragment order (same as verified round 2)
  for (int f = tid; f < 8192; f += 512) {
    int lane = f & 63, kk = (f >> 6) & 7, kt = (f >> 9) & 1, w2 = f >> 10;
    int row = 512 + w2 * 32 + kt * 16 + (lane & 15);
    int col = kk * 32 + (lane >> 4) * 8;
    *(short8*)(wlds + (size_t)f * 8) = *(const short8*)&whh_b[(size_t)row * HH + col];
  }

  // ---- is_init layout probe (verified round-1/2 logic) ----
  {
    const unsigned int* wq = (const unsigned int*)init_raw;
    int notf = 0, gt1 = 0, oddnz = 0;
    for (int i = tid; i < (BB * TT / 4); i += 512) {
      unsigned int v = wq[i];
      notf |= (v != 0u && v != 0x3F800000u);
      gt1 |= (v > 1u);
      if (i & 1) oddnz |= (v != 0u);
    }
    if (notf) atomicOr(&detf[0], 1);
    if (gt1) atomicOr(&detf[1], 1);
    if (oddnz) atomicOr(&detf[2], 1);
  }
  __syncthreads();
  if (tid < TT) {
    int layout = (!detf[0]) ? 1 : (detf[1] ? 0 : (detf[2] ? 1 : 2));
    int e = b * TT + tid;
    unsigned int v;
    if (layout == 0)      v = ((const unsigned char*)init_raw)[e];
    else if (layout == 1) v = ((const unsigned int*)init_raw)[e];
    else                  v = ((const unsigned int*)init_raw)[2 * e];
    msk[tid] = v ? 1 : 0;
  }

  const int l = tid & 63, w = tid >> 6;
  const int c = l & 15, g = l >> 4;
  const bool act = (c < AA);

  // resident W_hh tiles: r rows {32w,32w+16}, z rows {256+32w,256+32w+16}
  short8 wreg[4][8];
#pragma unroll
  for (int tile = 0; tile < 4; ++tile) {
    int row = (tile >> 1) * 256 + 32 * w + (tile & 1) * 16 + c;
#pragma unroll
    for (int kk = 0; kk < 8; ++kk)
      wreg[tile][kk] = *(const short8*)&whh_b[(size_t)row * HH + kk * 32 + g * 8];
  }
  const unsigned short* wl = wlds + w * 8192 + l * 8;

  // n-gate b_hh, hoisted to registers (independent of lane's c)
  f32x4 bn[2];
#pragma unroll
  for (int k2 = 0; k2 < 2; ++k2)
#pragma unroll
    for (int r = 0; r < 4; ++r)
      bn[k2][r] = bhh_g[2 * HH + 32 * w + k2 * 16 + g * 4 + r];

  __syncthreads();

  // gi prefetch registers (r,z already have b_ih+b_hh folded; n has b_ih)
  ushort4_t gc[6], gn_[6];
  if (act) {
    const unsigned short* gp = gi + ((size_t)(b * TT) * AA + c) * K3;
    const int j0w = 32 * w + g * 4;
    gc[0] = *(const ushort4_t*)(gp + j0w);
    gc[1] = *(const ushort4_t*)(gp + j0w + 16);
    gc[2] = *(const ushort4_t*)(gp + HH + j0w);
    gc[3] = *(const ushort4_t*)(gp + HH + j0w + 16);
    gc[4] = *(const ushort4_t*)(gp + 2 * HH + j0w);
    gc[5] = *(const ushort4_t*)(gp + 2 * HH + j0w + 16);
  }

  f32x4 hold[2];
  hold[0] = (f32x4){0.f, 0.f, 0.f, 0.f};
  hold[1] = (f32x4){0.f, 0.f, 0.f, 0.f};

  for (int t = 0; t < TT; ++t) {
    const int p = t & 1, np = 1 - p;
    const bool mskt = (msk[t] != 0);

    // prefetch gi for t+1 (hidden under this step's MFMAs)
    if (t + 1 < TT && act) {
      const unsigned short* gp = gi + ((size_t)(b * TT + t + 1) * AA + c) * K3;
      const int j0w = 32 * w + g * 4;
      gn_[0] = *(const ushort4_t*)(gp + j0w);
      gn_[1] = *(const ushort4_t*)(gp + j0w + 16);
      gn_[2] = *(const ushort4_t*)(gp + HH + j0w);
      gn_[3] = *(const ushort4_t*)(gp + HH + j0w + 16);
      gn_[4] = *(const ushort4_t*)(gp + 2 * HH + j0w);
      gn_[5] = *(const ushort4_t*)(gp + 2 * HH + j0w + 16);
    }

    f32x4 aR[2], aZ[2], aN[2];
#pragma unroll
    for (int k2 = 0; k2 < 2; ++k2) {
      aR[k2] = (f32x4){0.f, 0.f, 0.f, 0.f};
      aZ[k2] = (f32x4){0.f, 0.f, 0.f, 0.f};
      aN[k2] = (f32x4){0.f, 0.f, 0.f, 0.f};
    }
    if (mskt) {
      hold[0] = (f32x4){0.f, 0.f, 0.f, 0.f};
      hold[1] = (f32x4){0.f, 0.f, 0.f, 0.f};
    } else {
      // h bf16 fragments from conflict-free frag-order LDS (broadcast groups)
      short8 bhf[8];
#pragma unroll
      for (int kk = 0; kk < 8; ++kk)
        bhf[kk] = *(const short8*)(hsb + (((p * 128) + kk * 16 + (c & 3) * 4 + g) << 3));
#pragma unroll
      for (int kk = 0; kk < 8; ++kk) {
        aR[0] = __builtin_amdgcn_mfma_f32_16x16x32_bf16(wreg[0][kk], bhf[kk], aR[0], 0, 0, 0);
        aR[1] = __builtin_amdgcn_mfma_f32_16x16x32_bf16(wreg[1][kk], bhf[kk], aR[1], 0, 0, 0);
        aZ[0] = __builtin_amdgcn_mfma_f32_16x16x32_bf16(wreg[2][kk], bhf[kk], aZ[0], 0, 0, 0);
        aZ[1] = __builtin_amdgcn_mfma_f32_16x16x32_bf16(wreg[3][kk], bhf[kk], aZ[1], 0, 0, 0);
        short8 an0 = *(const short8*)(wl + kk * 512);
        short8 an1 = *(const short8*)(wl + 4096 + kk * 512);
        aN[0] = __builtin_amdgcn_mfma_f32_16x16x32_bf16(an0, bhf[kk], aN[0], 0, 0, 0);
        aN[1] = __builtin_amdgcn_mfma_f32_16x16x32_bf16(an1, bhf[kk], aN[1], 0, 0, 0);
      }
    }

    if (act) {
#pragma unroll
      for (int k2 = 0; k2 < 2; ++k2) {
        f32x4 hnv;
        ushort4_t hb4;
#pragma unroll
        for (int r = 0; r < 4; ++r) {
          const float pr = bf2f(gc[k2][r]) + aR[k2][r];
          const float pz = bf2f(gc[2 + k2][r]) + aZ[k2][r];
          const float rs = 1.f / (1.f + __expf(-pr));
          const float zs = 1.f / (1.f + __expf(-pz));
          const float hn = aN[k2][r] + bn[k2][r];
          const float pre = bf2f(gc[4 + k2][r]) + rs * hn;
          const float nn = 2.f / (1.f + __expf(-2.f * pre)) - 1.f;  // tanh
          const float hnew = fmaf(zs, hold[k2][r] - nn, nn);
          hnv[r] = hnew;
          hb4[r] = f2bf(hnew);
        }
        hold[k2] = hnv;
        // h bf16 -> frag-order LDS buf[np]: chunk (kk=w, a=c, g'=2k2+(g>>1))
        *(ushort4_t*)(hsb + (((np * 128) + w * 16 + c * 4 + (k2 * 2 + (g >> 1))) << 3) +
                      (g & 1) * 4) = hb4;
        const int j0 = 32 * w + k2 * 16 + g * 4;
        *(f32x4*)&out[(((size_t)b * TT + t) * AA + c) * HH + j0] = hnv;
        if (t == TT - 1)
          *(f32x4*)&out[(size_t)BB * TT * AA * HH + ((size_t)b * AA + c) * HH + j0] = hnv;
      }
    }
#pragma unroll
    for (int q = 0; q < 6; ++q) gc[q] = gn_[q];
    __syncthreads();
  }
}

// ---------------- Fallback: round-1 kernel (known-pass) ----------------
template <int WSW>
__global__ __launch_bounds__(512, 2) void gru_kernel(
    const float* __restrict__ x,
    const void* __restrict__ init_raw,
    const float* __restrict__ wih_f,
    const float* __restrict__ whh_f,
    const float* __restrict__ bih_g,
    const float* __restrict__ bhh_g,
    const unsigned short* __restrict__ wb,
    float* __restrict__ out) {
  __shared__ alignas(16) unsigned short xs[AA][II + 8];
  __shared__ alignas(16) unsigned short hsb[AA][HH + 8];
  __shared__ float hs32[AA][HH];
  __shared__ float gi_s[K3][5];
  __shared__ float gh_s[K3][5];
  __shared__ float bihs[K3];
  __shared__ float bhhs[K3];
  __shared__ unsigned char msk[TT];
  __shared__ int detf[3];

  const int tid = threadIdx.x;
  const int b = blockIdx.x;

  if (tid < 3) detf[tid] = 0;
  for (int i = tid; i < K3; i += 512) { bihs[i] = bih_g[i]; bhhs[i] = bhh_g[i]; }
  for (int i = tid; i < AA * HH; i += 512) {
    hs32[i >> 8][i & 255] = 0.f;
    hsb[i >> 8][i & 255] = 0;
  }
  __syncthreads();
  {
    const unsigned int* wq = (const unsigned int*)init_raw;
    int notf = 0, gt1 = 0, oddnz = 0;
    for (int i = tid; i < (BB * TT / 4); i += 512) {
      unsigned int v = wq[i];
      notf |= (v != 0u && v != 0x3F800000u);
      gt1 |= (v > 1u);
      if (i & 1) oddnz |= (v != 0u);
    }
    if (notf) atomicOr(&detf[0], 1);
    if (gt1) atomicOr(&detf[1], 1);
    if (oddnz) atomicOr(&detf[2], 1);
  }
  __syncthreads();
  if (tid < TT) {
    int layout = (!detf[0]) ? 1 : (detf[1] ? 0 : (detf[2] ? 1 : 2));
    int e = b * TT + tid;
    unsigned int v;
    if (layout == 0)      v = ((const unsigned char*)init_raw)[e];
    else if (layout == 1) v = ((const unsigned int*)init_raw)[e];
    else                  v = ((const unsigned int*)init_raw)[2 * e];
    msk[tid] = v ? 1 : 0;
  }
  __syncthreads();

  const int l = tid & 63;
  const int w = tid >> 6;
  const int c = l & 15;
  const int g = l >> 4;
  const bool act = (c < AA);
  const int xa = tid >> 7, xi = tid & 127;
  const float* xrow = x + (size_t)b * TT * AA * II;
  const unsigned short* wihb = wb;
  const unsigned short* whhb = wb + K3 * II;

  for (int t = 0; t < TT; ++t) {
    xs[xa][xi] = f2bf(xrow[(size_t)t * (AA * II) + tid]);
    if (msk[t]) {
      for (int i = tid; i < AA * HH; i += 512) {
        hs32[i >> 8][i & 255] = 0.f;
        hsb[i >> 8][i & 255] = 0;
      }
    }
    __syncthreads();

    short8 bx[4], bh[8];
    if (act) {
#pragma unroll
      for (int kk = 0; kk < 4; ++kk) bx[kk] = *(const short8*)&xs[c][kk * 32 + g * 8];
#pragma unroll
      for (int kk = 0; kk < 8; ++kk) bh[kk] = *(const short8*)&hsb[c][kk * 32 + g * 8];
    } else {
#pragma unroll
      for (int kk = 0; kk < 4; ++kk) bx[kk] = (short8)0;
#pragma unroll
      for (int kk = 0; kk < 8; ++kk) bh[kk] = (short8)0;
    }

#pragma unroll
    for (int kt = 0; kt < 6; ++kt) {
      const int ar = w * 96 + kt * 16 + c;
      f32x4 acc = {0.f, 0.f, 0.f, 0.f};
#pragma unroll
      for (int kk = 0; kk < 4; ++kk) {
        short8 aw;
        if (WSW) {
          aw = *(const short8*)&wihb[(size_t)ar * II + kk * 32 + g * 8];
        } else {
          const float* p = &wih_f[(size_t)ar * II + kk * 32 + g * 8];
#pragma unroll
          for (int e = 0; e < 8; ++e) aw[e] = (short)f2bf(p[e]);
        }
        acc = __builtin_amdgcn_mfma_f32_16x16x32_bf16(aw, bx[kk], acc, 0, 0, 0);
      }
      if (act) {
        const int dr = w * 96 + kt * 16 + g * 4;
#pragma unroll
        for (int r = 0; r < 4; ++r) gi_s[dr + r][c] = acc[r];
      }
    }

#pragma unroll
    for (int kt = 0; kt < 6; ++kt) {
      const int ar = w * 96 + kt * 16 + c;
      f32x4 acc = {0.f, 0.f, 0.f, 0.f};
#pragma unroll
      for (int kk = 0; kk < 8; ++kk) {
        short8 aw;
        if (WSW) {
          aw = *(const short8*)&whhb[(size_t)ar * HH + kk * 32 + g * 8];
        } else {
          const float* p = &whh_f[(size_t)ar * HH + kk * 32 + g * 8];
#pragma unroll
          for (int e = 0; e < 8; ++e) aw[e] = (short)f2bf(p[e]);
        }
        acc = __builtin_amdgcn_mfma_f32_16x16x32_bf16(aw, bh[kk], acc, 0, 0, 0);
      }
      if (act) {
        const int dr = w * 96 + kt * 16 + g * 4;
#pragma unroll
        for (int r = 0; r < 4; ++r) gh_s[dr + r][c] = acc[r];
      }
    }
    __syncthreads();

#pragma unroll
    for (int it = 0; it < 2; ++it) {
      const int idx = it * 512 + tid;
      const int a = idx >> 8, j = idx & 255;
      const float ir = gi_s[j][a] + bihs[j];
      const float iz = gi_s[HH + j][a] + bihs[HH + j];
      const float inn = gi_s[2 * HH + j][a] + bihs[2 * HH + j];
      const float hr = gh_s[j][a] + bhhs[j];
      const float hz = gh_s[HH + j][a] + bhhs[HH + j];
      const float hn = gh_s[2 * HH + j][a] + bhhs[2 * HH + j];
      const float r = 1.f / (1.f + __expf(-(ir + hr)));
      const float z = 1.f / (1.f + __expf(-(iz + hz)));
      const float pre = inn + r * hn;
      const float ea = __expf(-2.f * fabsf(pre));
      float n = (1.f - ea) / (1.f + ea);
      n = (pre < 0.f) ? -n : n;
      const float hold = hs32[a][j];
      const float hnew = (1.f - z) * n + z * hold;
      hs32[a][j] = hnew;
      hsb[a][j] = f2bf(hnew);
      out[(((size_t)b * TT + t) * AA + a) * HH + j] = hnew;
      if (t == TT - 1)
        out[(size_t)BB * TT * AA * HH + ((size_t)b * AA + a) * HH + j] = hnew;
    }
    __syncthreads();
  }
}

extern "C" void kernel_launch(void* const* d_in, const int* in_sizes, int n_in,
                              void* d_out, int out_size, void* d_ws, size_t ws_size,
                              hipStream_t stream) {
  (void)in_sizes; (void)n_in; (void)out_size;
  const float* x = (const float*)d_in[0];
  const void* is_init = d_in[1];
  const float* wih = (const float*)d_in[2];
  const float* whh = (const float*)d_in[3];
  const float* bih = (const float*)d_in[4];
  const float* bhh = (const float*)d_in[5];
  float* out = (float*)d_out;

  const size_t W_ELS = (size_t)(K3 * II + K3 * HH);        // 294,912
  const size_t W_BYTES = W_ELS * 2;                        // 589,824
  const size_t GI_BYTES = (size_t)BB * TT * AA * K3 * 2;   // 201,326,592
  const int SMEM = 135312;

  if (ws_size >= W_BYTES + GI_BYTES) {
    hipError_t e = hipFuncSetAttribute(
        (const void*)rnn_kernel, hipFuncAttributeMaxDynamicSharedMemorySize, SMEM);
    if (e == hipSuccess) {
      unsigned short* wb = (unsigned short*)d_ws;
      unsigned short* gi = wb + W_ELS;
      wconv_kernel<<<(int)(W_ELS / 512), 512, 0, stream>>>(wih, whh, wb);
      gi_kernel<<<2048, 512, 0, stream>>>(x, bih, bhh, wb, gi);
      rnn_kernel<<<BB, 512, SMEM, stream>>>(is_init, bhh, wb, gi, out);
      return;
    }
  }
  // fallback (round-1 verified path)
  if (ws_size >= W_BYTES) {
    unsigned short* wb = (unsigned short*)d_ws;
    wconv_kernel<<<(int)(W_ELS / 512), 512, 0, stream>>>(wih, whh, wb);
    gru_kernel<1><<<BB, 512, 0, stream>>>(x, is_init, wih, whh, bih, bhh, wb, out);
  } else {
    gru_kernel<0><<<BB, 512, 0, stream>>>(x, is_init, wih, whh, bih, bhh, nullptr, out);
  }
}

// Round 4
// 326.388 us; speedup vs baseline: 4.3496x; 1.3035x over previous
//
#include <hip/hip_runtime.h>
#include <cstdint>
#include <cstddef>

#define BB 256
#define TT 128
#define AA 4
#define II 128
#define HH 256
#define K3 768  // 3*H

typedef __attribute__((ext_vector_type(8))) short short8;
typedef __attribute__((ext_vector_type(4))) float f32x4;
typedef __attribute__((ext_vector_type(4))) unsigned short ushort4_t;

static __device__ __forceinline__ unsigned short f2bf(float f) {
  unsigned int b = __float_as_uint(f);
  return (unsigned short)((b + 0x7FFFu + ((b >> 16) & 1u)) >> 16);  // RNE
}
static __device__ __forceinline__ float bf2f(unsigned short u) {
  return __uint_as_float(((unsigned int)u) << 16);
}

// fp32 -> bf16 weight conversion into workspace (W_ih then W_hh, row-major kept)
__global__ void wconv_kernel(const float* __restrict__ wih,
                             const float* __restrict__ whh,
                             unsigned short* __restrict__ o) {
  int i = blockIdx.x * 512 + threadIdx.x;
  float v = (i < K3 * II) ? wih[i] : whh[i - K3 * II];
  o[i] = f2bf(v);
}

// ---------------- Phase A: gi = x * W_ih^T + b_ih (+ b_hh for r,z), bf16 ----
__global__ __launch_bounds__(512, 2) void gi_kernel(
    const float* __restrict__ x,
    const float* __restrict__ bih_g,
    const float* __restrict__ bhh_g,
    const unsigned short* __restrict__ wb,   // W_ih bf16 at ws[0]
    unsigned short* __restrict__ gi) {
  __shared__ alignas(16) unsigned short xs[64][144];
  __shared__ alignas(16) unsigned short gst[16][792];
  __shared__ float bihs[K3];

  const int tid = threadIdx.x;
  const int l = tid & 63, w = tid >> 6;
  const int c = l & 15, g = l >> 4;
  const size_t m0 = (size_t)blockIdx.x * 64;

  for (int i = tid; i < K3; i += 512)
    bihs[i] = bih_g[i] + (i < 2 * HH ? bhh_g[i] : 0.f);
  for (int i = tid; i < 64 * 128; i += 512) {
    int row = i >> 7, col = i & 127;
    xs[row][col] = f2bf(x[m0 * 128 + i]);
  }
  short8 wf[6][4];
#pragma unroll
  for (int kt = 0; kt < 6; ++kt) {
    int row = 96 * w + kt * 16 + c;
#pragma unroll
    for (int kk = 0; kk < 4; ++kk)
      wf[kt][kk] = *(const short8*)&wb[(size_t)row * II + kk * 32 + g * 8];
  }
  __syncthreads();

  for (int chunk = 0; chunk < 4; ++chunk) {
    short8 bx[4];
#pragma unroll
    for (int kk = 0; kk < 4; ++kk)
      bx[kk] = *(const short8*)&xs[chunk * 16 + c][kk * 32 + g * 8];
    f32x4 acc[6];
#pragma unroll
    for (int kt = 0; kt < 6; ++kt) acc[kt] = (f32x4){0.f, 0.f, 0.f, 0.f};
#pragma unroll
    for (int kt = 0; kt < 6; ++kt)
#pragma unroll
      for (int kk = 0; kk < 4; ++kk)
        acc[kt] = __builtin_amdgcn_mfma_f32_16x16x32_bf16(wf[kt][kk], bx[kk], acc[kt], 0, 0, 0);
#pragma unroll
    for (int kt = 0; kt < 6; ++kt) {
      int gate0 = 96 * w + kt * 16 + g * 4;
      ushort4_t p;
#pragma unroll
      for (int r = 0; r < 4; ++r) p[r] = f2bf(acc[kt][r] + bihs[gate0 + r]);
      *(ushort4_t*)&gst[c][gate0] = p;
    }
    __syncthreads();
    for (int i = tid; i < 16 * 96; i += 512) {
      int row = i / 96, seg = i - row * 96;
      *(short8*)(gi + (m0 + chunk * 16 + row) * K3 + seg * 8) =
          *(const short8*)&gst[row][seg * 8];
    }
    __syncthreads();
  }
}

// ---------------- Phase B: recurrence ----------------
// grid 256 (block = batch b), 512 thr (8 waves). Wave w owns units
// [32w,32w+32): r/z W_hh tiles in AGPRs, n tiles in LDS frag-order.
// h fp32 in owner-lane registers; h bf16 ping-pong frag-order LDS.
// t-loop unrolled x2 (static buffer parity, named gi ping-pong regs).
// Transcendentals: exp2/rcp intrinsics (no IEEE-div expansion).
__global__ __launch_bounds__(512, 2) void rnn_kernel(
    const void* __restrict__ init_raw,
    const float* __restrict__ bhh_g,
    const unsigned short* __restrict__ wsb,  // ws bf16 base: [W_ih | W_hh]
    const unsigned short* __restrict__ gi,
    float* __restrict__ out) {
  extern __shared__ char smem[];
  unsigned short* wlds = (unsigned short*)smem;             // 131072 B (n-gate W)
  unsigned short* hsb = (unsigned short*)(smem + 131072);   // 2 bufs x 2048 B
  unsigned char* msk = (unsigned char*)(smem + 135168);     // 128 B
  int* detf = (int*)(smem + 135296);                        // 12 B

  const int tid = threadIdx.x;
  const int b = blockIdx.x;
  const unsigned short* whh_b = wsb + K3 * II;

  if (tid < 3) detf[tid] = 0;
  for (int i = tid; i < 2048; i += 512) *(unsigned short*)&hsb[i] = 0;
  for (int f = tid; f < 8192; f += 512) {
    int lane = f & 63, kk = (f >> 6) & 7, kt = (f >> 9) & 1, w2 = f >> 10;
    int row = 512 + w2 * 32 + kt * 16 + (lane & 15);
    int col = kk * 32 + (lane >> 4) * 8;
    *(short8*)(wlds + (size_t)f * 8) = *(const short8*)&whh_b[(size_t)row * HH + col];
  }

  // ---- is_init layout probe (verified) ----
  {
    const unsigned int* wq = (const unsigned int*)init_raw;
    int notf = 0, gt1 = 0, oddnz = 0;
    for (int i = tid; i < (BB * TT / 4); i += 512) {
      unsigned int v = wq[i];
      notf |= (v != 0u && v != 0x3F800000u);
      gt1 |= (v > 1u);
      if (i & 1) oddnz |= (v != 0u);
    }
    if (notf) atomicOr(&detf[0], 1);
    if (gt1) atomicOr(&detf[1], 1);
    if (oddnz) atomicOr(&detf[2], 1);
  }
  __syncthreads();
  if (tid < TT) {
    int layout = (!detf[0]) ? 1 : (detf[1] ? 0 : (detf[2] ? 1 : 2));
    int e = b * TT + tid;
    unsigned int v;
    if (layout == 0)      v = ((const unsigned char*)init_raw)[e];
    else if (layout == 1) v = ((const unsigned int*)init_raw)[e];
    else                  v = ((const unsigned int*)init_raw)[2 * e];
    msk[tid] = v ? 1 : 0;
  }

  const int l = tid & 63, w = tid >> 6;
  const int c = l & 15, g = l >> 4;
  const bool act = (c < AA);

  // resident W_hh tiles: r rows {32w,32w+16}, z rows {256+32w,256+32w+16}
  short8 wreg[4][8];
#pragma unroll
  for (int tile = 0; tile < 4; ++tile) {
    int row = (tile >> 1) * 256 + 32 * w + (tile & 1) * 16 + c;
#pragma unroll
    for (int kk = 0; kk < 8; ++kk)
      wreg[tile][kk] = *(const short8*)&whh_b[(size_t)row * HH + kk * 32 + g * 8];
  }
  const unsigned short* wl = wlds + w * 8192 + l * 8;

  // n-gate b_hh, hoisted to registers
  f32x4 bn[2];
#pragma unroll
  for (int k2 = 0; k2 < 2; ++k2)
#pragma unroll
    for (int r = 0; r < 4; ++r)
      bn[k2][r] = bhh_g[2 * HH + 32 * w + k2 * 16 + g * 4 + r];

  __syncthreads();

  // induction pointers (imm-offset loads/stores, one bump per t)
  const unsigned short* gp =
      gi + ((size_t)(b * TT) * AA + (c & 3)) * K3 + 32 * w + g * 4;
  float* op = out + ((size_t)(b * TT) * AA + c) * HH + 32 * w + g * 4;
  const unsigned short* hrd = hsb + ((c & 3) * 4 + g) * 8;            // read base
  unsigned short* hwr = hsb + (w * 16 + c * 4 + (g >> 1)) * 8 + (g & 1) * 4;

  f32x4 hold[2];
  hold[0] = (f32x4){0.f, 0.f, 0.f, 0.f};
  hold[1] = (f32x4){0.f, 0.f, 0.f, 0.f};

  ushort4_t gcA[6], gcB[6];

#define GI_LOAD(GC)                               \
  do {                                            \
    GC[0] = *(const ushort4_t*)(gp);              \
    GC[1] = *(const ushort4_t*)(gp + 16);         \
    GC[2] = *(const ushort4_t*)(gp + 256);        \
    GC[3] = *(const ushort4_t*)(gp + 272);        \
    GC[4] = *(const ushort4_t*)(gp + 512);        \
    GC[5] = *(const ushort4_t*)(gp + 528);        \
    gp += AA * K3;                                \
  } while (0)

#define L2E 1.44269504088896f

#define STEP(TI, P, GC)                                                           \
  do {                                                                            \
    const bool mskt = (msk[TI] != 0);                                             \
    f32x4 aR[2], aZ[2], aN[2];                                                    \
    _Pragma("unroll") for (int k2 = 0; k2 < 2; ++k2) {                            \
      aR[k2] = (f32x4){0.f, 0.f, 0.f, 0.f};                                       \
      aZ[k2] = (f32x4){0.f, 0.f, 0.f, 0.f};                                       \
      aN[k2] = (f32x4){0.f, 0.f, 0.f, 0.f};                                       \
    }                                                                             \
    if (mskt) {                                                                   \
      hold[0] = (f32x4){0.f, 0.f, 0.f, 0.f};                                      \
      hold[1] = (f32x4){0.f, 0.f, 0.f, 0.f};                                      \
    } else {                                                                      \
      short8 bhf[8];                                                              \
      _Pragma("unroll") for (int kk = 0; kk < 8; ++kk)                            \
          bhf[kk] = *(const short8*)(hrd + (P) * 1024 + kk * 128);                \
      _Pragma("unroll") for (int kk = 0; kk < 8; ++kk) {                          \
        aR[0] = __builtin_amdgcn_mfma_f32_16x16x32_bf16(wreg[0][kk], bhf[kk], aR[0], 0, 0, 0); \
        aR[1] = __builtin_amdgcn_mfma_f32_16x16x32_bf16(wreg[1][kk], bhf[kk], aR[1], 0, 0, 0); \
        aZ[0] = __builtin_amdgcn_mfma_f32_16x16x32_bf16(wreg[2][kk], bhf[kk], aZ[0], 0, 0, 0); \
        aZ[1] = __builtin_amdgcn_mfma_f32_16x16x32_bf16(wreg[3][kk], bhf[kk], aZ[1], 0, 0, 0); \
        short8 an0 = *(const short8*)(wl + kk * 512);                             \
        short8 an1 = *(const short8*)(wl + 4096 + kk * 512);                      \
        aN[0] = __builtin_amdgcn_mfma_f32_16x16x32_bf16(an0, bhf[kk], aN[0], 0, 0, 0); \
        aN[1] = __builtin_amdgcn_mfma_f32_16x16x32_bf16(an1, bhf[kk], aN[1], 0, 0, 0); \
      }                                                                           \
    }                                                                             \
    if (act) {                                                                    \
      _Pragma("unroll") for (int k2 = 0; k2 < 2; ++k2) {                          \
        f32x4 hnv;                                                                \
        ushort4_t hb4;                                                            \
        _Pragma("unroll") for (int r = 0; r < 4; ++r) {                           \
          const float pr = bf2f(GC[k2][r]) + aR[k2][r];                           \
          const float pz = bf2f(GC[2 + k2][r]) + aZ[k2][r];                       \
          const float rs = __builtin_amdgcn_rcpf(1.f + __builtin_amdgcn_exp2f(-pr * L2E)); \
          const float zs = __builtin_amdgcn_rcpf(1.f + __builtin_amdgcn_exp2f(-pz * L2E)); \
          const float hn = aN[k2][r] + bn[k2][r];                                 \
          const float pre = bf2f(GC[4 + k2][r]) + rs * hn;                        \
          const float e2 = __builtin_amdgcn_exp2f(pre * (2.f * L2E));             \
          const float nn = 1.f - 2.f * __builtin_amdgcn_rcpf(1.f + e2);           \
          const float hnew = fmaf(zs, hold[k2][r] - nn, nn);                      \
          hnv[r] = hnew;                                                          \
          hb4[r] = f2bf(hnew);                                                    \
        }                                                                         \
        hold[k2] = hnv;                                                           \
        *(ushort4_t*)(hwr + (1 - (P)) * 1024 + k2 * 16) = hb4;                    \
        *(f32x4*)(op + k2 * 16) = hnv;                                            \
      }                                                                           \
    }                                                                             \
    op += AA * HH;                                                                \
  } while (0)

  GI_LOAD(gcA);  // t = 0
  for (int t = 0; t < TT - 2; t += 2) {
    GI_LOAD(gcB);  // t+1
    STEP(t, 0, gcA);
    __syncthreads();
    GI_LOAD(gcA);  // t+2
    STEP(t + 1, 1, gcB);
    __syncthreads();
  }
  {
    GI_LOAD(gcB);  // t = 127
    STEP(TT - 2, 0, gcA);
    __syncthreads();
    STEP(TT - 1, 1, gcB);
  }

  if (act) {
    float* hp = out + (size_t)BB * TT * AA * HH + ((size_t)b * AA + c) * HH + 32 * w + g * 4;
    *(f32x4*)hp = hold[0];
    *(f32x4*)(hp + 16) = hold[1];
  }
#undef GI_LOAD
#undef STEP
}

// ---------------- Fallback: round-1 kernel (known-pass) ----------------
template <int WSW>
__global__ __launch_bounds__(512, 2) void gru_kernel(
    const float* __restrict__ x,
    const void* __restrict__ init_raw,
    const float* __restrict__ wih_f,
    const float* __restrict__ whh_f,
    const float* __restrict__ bih_g,
    const float* __restrict__ bhh_g,
    const unsigned short* __restrict__ wb,
    float* __restrict__ out) {
  __shared__ alignas(16) unsigned short xs[AA][II + 8];
  __shared__ alignas(16) unsigned short hsb[AA][HH + 8];
  __shared__ float hs32[AA][HH];
  __shared__ float gi_s[K3][5];
  __shared__ float gh_s[K3][5];
  __shared__ float bihs[K3];
  __shared__ float bhhs[K3];
  __shared__ unsigned char msk[TT];
  __shared__ int detf[3];

  const int tid = threadIdx.x;
  const int b = blockIdx.x;

  if (tid < 3) detf[tid] = 0;
  for (int i = tid; i < K3; i += 512) { bihs[i] = bih_g[i]; bhhs[i] = bhh_g[i]; }
  for (int i = tid; i < AA * HH; i += 512) {
    hs32[i >> 8][i & 255] = 0.f;
    hsb[i >> 8][i & 255] = 0;
  }
  __syncthreads();
  {
    const unsigned int* wq = (const unsigned int*)init_raw;
    int notf = 0, gt1 = 0, oddnz = 0;
    for (int i = tid; i < (BB * TT / 4); i += 512) {
      unsigned int v = wq[i];
      notf |= (v != 0u && v != 0x3F800000u);
      gt1 |= (v > 1u);
      if (i & 1) oddnz |= (v != 0u);
    }
    if (notf) atomicOr(&detf[0], 1);
    if (gt1) atomicOr(&detf[1], 1);
    if (oddnz) atomicOr(&detf[2], 1);
  }
  __syncthreads();
  if (tid < TT) {
    int layout = (!detf[0]) ? 1 : (detf[1] ? 0 : (detf[2] ? 1 : 2));
    int e = b * TT + tid;
    unsigned int v;
    if (layout == 0)      v = ((const unsigned char*)init_raw)[e];
    else if (layout == 1) v = ((const unsigned int*)init_raw)[e];
    else                  v = ((const unsigned int*)init_raw)[2 * e];
    msk[tid] = v ? 1 : 0;
  }
  __syncthreads();

  const int l = tid & 63;
  const int w = tid >> 6;
  const int c = l & 15;
  const int g = l >> 4;
  const bool act = (c < AA);
  const int xa = tid >> 7, xi = tid & 127;
  const float* xrow = x + (size_t)b * TT * AA * II;
  const unsigned short* wihb = wb;
  const unsigned short* whhb = wb + K3 * II;

  for (int t = 0; t < TT; ++t) {
    xs[xa][xi] = f2bf(xrow[(size_t)t * (AA * II) + tid]);
    if (msk[t]) {
      for (int i = tid; i < AA * HH; i += 512) {
        hs32[i >> 8][i & 255] = 0.f;
        hsb[i >> 8][i & 255] = 0;
      }
    }
    __syncthreads();

    short8 bx[4], bh[8];
    if (act) {
#pragma unroll
      for (int kk = 0; kk < 4; ++kk) bx[kk] = *(const short8*)&xs[c][kk * 32 + g * 8];
#pragma unroll
      for (int kk = 0; kk < 8; ++kk) bh[kk] = *(const short8*)&hsb[c][kk * 32 + g * 8];
    } else {
#pragma unroll
      for (int kk = 0; kk < 4; ++kk) bx[kk] = (short8)0;
#pragma unroll
      for (int kk = 0; kk < 8; ++kk) bh[kk] = (short8)0;
    }

#pragma unroll
    for (int kt = 0; kt < 6; ++kt) {
      const int ar = w * 96 + kt * 16 + c;
      f32x4 acc = {0.f, 0.f, 0.f, 0.f};
#pragma unroll
      for (int kk = 0; kk < 4; ++kk) {
        short8 aw;
        if (WSW) {
          aw = *(const short8*)&wihb[(size_t)ar * II + kk * 32 + g * 8];
        } else {
          const float* p = &wih_f[(size_t)ar * II + kk * 32 + g * 8];
#pragma unroll
          for (int e = 0; e < 8; ++e) aw[e] = (short)f2bf(p[e]);
        }
        acc = __builtin_amdgcn_mfma_f32_16x16x32_bf16(aw, bx[kk], acc, 0, 0, 0);
      }
      if (act) {
        const int dr = w * 96 + kt * 16 + g * 4;
#pragma unroll
        for (int r = 0; r < 4; ++r) gi_s[dr + r][c] = acc[r];
      }
    }

#pragma unroll
    for (int kt = 0; kt < 6; ++kt) {
      const int ar = w * 96 + kt * 16 + c;
      f32x4 acc = {0.f, 0.f, 0.f, 0.f};
#pragma unroll
      for (int kk = 0; kk < 8; ++kk) {
        short8 aw;
        if (WSW) {
          aw = *(const short8*)&whhb[(size_t)ar * HH + kk * 32 + g * 8];
        } else {
          const float* p = &whh_f[(size_t)ar * HH + kk * 32 + g * 8];
#pragma unroll
          for (int e = 0; e < 8; ++e) aw[e] = (short)f2bf(p[e]);
        }
        acc = __builtin_amdgcn_mfma_f32_16x16x32_bf16(aw, bh[kk], acc, 0, 0, 0);
      }
      if (act) {
        const int dr = w * 96 + kt * 16 + g * 4;
#pragma unroll
        for (int r = 0; r < 4; ++r) gh_s[dr + r][c] = acc[r];
      }
    }
    __syncthreads();

#pragma unroll
    for (int it = 0; it < 2; ++it) {
      const int idx = it * 512 + tid;
      const int a = idx >> 8, j = idx & 255;
      const float ir = gi_s[j][a] + bihs[j];
      const float iz = gi_s[HH + j][a] + bihs[HH + j];
      const float inn = gi_s[2 * HH + j][a] + bihs[2 * HH + j];
      const float hr = gh_s[j][a] + bhhs[j];
      const float hz = gh_s[HH + j][a] + bhhs[HH + j];
      const float hn = gh_s[2 * HH + j][a] + bhhs[2 * HH + j];
      const float r = 1.f / (1.f + __expf(-(ir + hr)));
      const float z = 1.f / (1.f + __expf(-(iz + hz)));
      const float pre = inn + r * hn;
      const float ea = __expf(-2.f * fabsf(pre));
      float n = (1.f - ea) / (1.f + ea);
      n = (pre < 0.f) ? -n : n;
      const float hold = hs32[a][j];
      const float hnew = (1.f - z) * n + z * hold;
      hs32[a][j] = hnew;
      hsb[a][j] = f2bf(hnew);
      out[(((size_t)b * TT + t) * AA + a) * HH + j] = hnew;
      if (t == TT - 1)
        out[(size_t)BB * TT * AA * HH + ((size_t)b * AA + a) * HH + j] = hnew;
    }
    __syncthreads();
  }
}

extern "C" void kernel_launch(void* const* d_in, const int* in_sizes, int n_in,
                              void* d_out, int out_size, void* d_ws, size_t ws_size,
                              hipStream_t stream) {
  (void)in_sizes; (void)n_in; (void)out_size;
  const float* x = (const float*)d_in[0];
  const void* is_init = d_in[1];
  const float* wih = (const float*)d_in[2];
  const float* whh = (const float*)d_in[3];
  const float* bih = (const float*)d_in[4];
  const float* bhh = (const float*)d_in[5];
  float* out = (float*)d_out;

  const size_t W_ELS = (size_t)(K3 * II + K3 * HH);        // 294,912
  const size_t W_BYTES = W_ELS * 2;                        // 589,824
  const size_t GI_BYTES = (size_t)BB * TT * AA * K3 * 2;   // 201,326,592
  const int SMEM = 135312;

  if (ws_size >= W_BYTES + GI_BYTES) {
    hipError_t e = hipFuncSetAttribute(
        (const void*)rnn_kernel, hipFuncAttributeMaxDynamicSharedMemorySize, SMEM);
    if (e == hipSuccess) {
      unsigned short* wb = (unsigned short*)d_ws;
      unsigned short* gi = wb + W_ELS;
      wconv_kernel<<<(int)(W_ELS / 512), 512, 0, stream>>>(wih, whh, wb);
      gi_kernel<<<2048, 512, 0, stream>>>(x, bih, bhh, wb, gi);
      rnn_kernel<<<BB, 512, SMEM, stream>>>(is_init, bhh, wb, gi, out);
      return;
    }
  }
  // fallback (round-1 verified path)
  if (ws_size >= W_BYTES) {
    unsigned short* wb = (unsigned short*)d_ws;
    wconv_kernel<<<(int)(W_ELS / 512), 512, 0, stream>>>(wih, whh, wb);
    gru_kernel<1><<<BB, 512, 0, stream>>>(x, is_init, wih, whh, bih, bhh, wb, out);
  } else {
    gru_kernel<0><<<BB, 512, 0, stream>>>(x, is_init, wih, whh, bih, bhh, nullptr, out);
  }
}